// Round 19
// baseline (53.707 us; speedup 1.0000x reference)
//
#include <hip/hip_runtime.h>
#include <stdint.h>

#define B_ 512
#define M_ 32
#define D_ 2048
#define Q4 128   // float4 per row per quarter (512 cols)

typedef float fvec4 __attribute__((ext_vector_type(4)));

static __device__ __forceinline__ uint32_t pk_bf16(float lo, float hi) {
    uint32_t r;
    asm("v_cvt_pk_bf16_f32 %0, %1, %2" : "=v"(r) : "v"(lo), "v"(hi));
    return r;
}
static __device__ __forceinline__ float bf_lo(uint32_t u) { return __uint_as_float(u << 16); }
static __device__ __forceinline__ float bf_hi(uint32_t u) { return __uint_as_float(u & 0xFFFF0000u); }

// LDS-only barrier: orders ds ops across waves but does NOT drain vmcnt --
// global loads stay in flight and nontemporal stores never block the barrier.
static __device__ __forceinline__ void lds_barrier() {
    asm volatile("s_waitcnt lgkmcnt(0)" ::: "memory");
    __builtin_amdgcn_s_barrier();
}

// 256 blocks (1/CU), 1024 threads, 2 batches/block, 4x32KB LDS quarter-buffers.
// vs R18 (47.26us): coefs computed wave-redundantly into REGISTERS (kills the
// sC LDS round-trip and 2 of 8 barriers; CO-A's VALU hides under in-flight
// batch-B loads), and batch-B's first two quarter-loads issue BEFORE the coef
// bubble so the HBM read engine never idles.
__global__ __launch_bounds__(1024, 4) void ephaptic_pipe(const float* __restrict__ x,
                                                         const float* __restrict__ w,
                                                         float* __restrict__ out) {
    const int tid = threadIdx.x;
    const int b0 = blockIdx.x * 2;

    __shared__ uint32_t sx[4][M_][256];     // 4 quarter-buffers, bf16 pairs (32 KB each)
    __shared__ float sT[M_], sF[M_], sL[M_];

    // R-mapping: thread (m,t) covers row m, 4 float4s per quarter
    const int m = tid >> 5;
    const int t = tid & 31;
    // W-mapping: thread (rg,p4) covers col4 p4 for rows rg*4..rg*4+3
    const int p4 = tid & 127;
    const int rg = tid >> 7;
    const int lane = tid & 63;

    const fvec4* wf = (const fvec4*)w;

    float psum = 0.f, first = 0.f, last = 0.f;
    fvec4 a0, a1, a2, a3;   // load set A (even quarters)
    fvec4 e0, e1, e2, e3;   // load set B (odd quarters)
    float cc[4][3];         // per-thread coefs for its 4 written rows (regs)

    auto RL = [&](int b, int rq, fvec4& v0, fvec4& v1, fvec4& v2, fvec4& v3) {
        const fvec4* row = (const fvec4*)(x + ((size_t)b * M_ + m) * (size_t)D_) + rq * Q4;
        v0 = row[t];  v1 = row[t + 32];  v2 = row[t + 64];  v3 = row[t + 96];
    };
    auto RS = [&](int rq, const fvec4& v0, const fvec4& v1, const fvec4& v2, const fvec4& v3) {
        psum += (v0.x+v0.y)+(v0.z+v0.w) + (v1.x+v1.y)+(v1.z+v1.w)
              + (v2.x+v2.y)+(v2.z+v2.w) + (v3.x+v3.y)+(v3.z+v3.w);
        if (rq == 0 && t == 0)  first = v0.x;   // x[m][0]
        if (rq == 3 && t == 31) last  = v3.w;   // x[m][2047]
        uint2* sr = (uint2*)sx[rq][m];
        sr[t]      = make_uint2(pk_bf16(v0.x, v0.y), pk_bf16(v0.z, v0.w));
        sr[t + 32] = make_uint2(pk_bf16(v1.x, v1.y), pk_bf16(v1.z, v1.w));
        sr[t + 64] = make_uint2(pk_bf16(v2.x, v2.y), pk_bf16(v2.z, v2.w));
        sr[t + 96] = make_uint2(pk_bf16(v3.x, v3.y), pk_bf16(v3.z, v3.w));
    };
    auto SUMS = [&]() {
        float s = psum;
#pragma unroll
        for (int off = 16; off > 0; off >>= 1) s += __shfl_xor(s, off, 64);
        if (t == 0)  { sT[m] = s; sF[m] = first; }
        if (t == 31) { sL[m] = last; }
    };
    // wave-redundant coef: lane l computes row rg*4+(l&3); distribute via shfl.
    // sT[j] reads are lane-uniform (broadcast, conflict-free).
    auto CO = [&]() {
        const int i = rg * 4 + (lane & 3);
        float r0 = 0.f, r1 = 0.f, r2 = 0.f;
        for (int j = 0; j < M_; ++j) {
            const float dij = (j == i) ? 0.f : __expf(-0.5f * fabsf((float)(i - j)));
            const float T = sT[j];
            r0 += dij * (T - sL[j]);
            r1 += dij * T;
            r2 += dij * (T - sF[j]);
        }
        const float s = 0.1f / (float)D_;
        r0 *= s; r1 *= s; r2 *= s;
#pragma unroll
        for (int rr = 0; rr < 4; ++rr) {
            const int src = (lane & ~3) | rr;
            cc[rr][0] = __shfl(r0, src, 64);
            cc[rr][1] = __shfl(r1, src, 64);
            cc[rr][2] = __shfl(r2, src, 64);
        }
    };
    auto W = [&](int b, int wq) {
        const fvec4 w0 = wf[(wq * Q4 + p4) * 3 + 0];
        const fvec4 w1 = wf[(wq * Q4 + p4) * 3 + 1];
        const fvec4 w2 = wf[(wq * Q4 + p4) * 3 + 2];
        fvec4* ob = (fvec4*)(out + (size_t)b * M_ * D_) + wq * Q4 + p4;
#pragma unroll
        for (int rr = 0; rr < 4; ++rr) {
            const int r = rg * 4 + rr;
            const uint2 u = ((const uint2*)sx[wq][r])[p4];
            fvec4 o;
            o.x = bf_lo(u.x) + cc[rr][0] * w0.x + cc[rr][1] * w0.y + cc[rr][2] * w0.z;
            o.y = bf_hi(u.x) + cc[rr][0] * w0.w + cc[rr][1] * w1.x + cc[rr][2] * w1.y;
            o.z = bf_lo(u.y) + cc[rr][0] * w1.z + cc[rr][1] * w1.w + cc[rr][2] * w2.x;
            o.w = bf_hi(u.y) + cc[rr][0] * w2.y + cc[rr][1] * w2.z + cc[rr][2] * w2.w;
            __builtin_nontemporal_store(o, ob + (size_t)r * 512);
        }
    };

    // ---- batch A reads: 2-deep register pipeline
    RL(b0, 0, a0, a1, a2, a3);
    RL(b0, 1, e0, e1, e2, e3);
    RS(0, a0, a1, a2, a3);  RL(b0, 2, a0, a1, a2, a3);
    RS(1, e0, e1, e2, e3);  RL(b0, 3, e0, e1, e2, e3);
    RS(2, a0, a1, a2, a3);
    RS(3, e0, e1, e2, e3);
    SUMS();
    // early-issue batch B quarters 0,1 -- in flight through the coef bubble
    RL(b0 + 1, 0, a0, a1, a2, a3);
    RL(b0 + 1, 1, e0, e1, e2, e3);
    lds_barrier();              // sT/sF/sL visible; sx[0..3] complete
    CO();                       // batch-A coefs into registers (hidden under B loads)
    W(b0, 0);
    lds_barrier();              // all waves done reading sx[0] (+ CO's sT reads done)
    psum = 0.f;
    RS(0, a0, a1, a2, a3);  RL(b0 + 1, 2, a0, a1, a2, a3);  W(b0, 1);
    lds_barrier();
    RS(1, e0, e1, e2, e3);  RL(b0 + 1, 3, e0, e1, e2, e3);  W(b0, 2);
    lds_barrier();
    RS(2, a0, a1, a2, a3);  W(b0, 3);
    lds_barrier();
    RS(3, e0, e1, e2, e3);
    SUMS();
    lds_barrier();              // sT-B visible; sx[0..3] refilled with batch B
    CO();                       // batch-B coefs
    // ---- batch B: drain writes (stores retire past endpgm)
    W(b0 + 1, 0);
    W(b0 + 1, 1);
    W(b0 + 1, 2);
    W(b0 + 1, 3);
}

extern "C" void kernel_launch(void* const* d_in, const int* in_sizes, int n_in,
                              void* d_out, int out_size, void* d_ws, size_t ws_size,
                              hipStream_t stream) {
    const float* x = (const float*)d_in[0];
    const float* w = (const float*)d_in[1];
    float* out = (float*)d_out;
    ephaptic_pipe<<<B_ / 2, 1024, 0, stream>>>(x, w, out);
}

// Round 20
// 46.776 us; speedup vs baseline: 1.1482x; 1.1482x over previous
//
#include <hip/hip_runtime.h>
#include <stdint.h>

#define B_ 512
#define M_ 32
#define D_ 2048
#define Q4 128   // float4 per row per quarter (512 cols)

typedef float fvec4 __attribute__((ext_vector_type(4)));

static __device__ __forceinline__ uint32_t pk_bf16(float lo, float hi) {
    uint32_t r;
    asm("v_cvt_pk_bf16_f32 %0, %1, %2" : "=v"(r) : "v"(lo), "v"(hi));
    return r;
}
static __device__ __forceinline__ float bf_lo(uint32_t u) { return __uint_as_float(u << 16); }
static __device__ __forceinline__ float bf_hi(uint32_t u) { return __uint_as_float(u & 0xFFFF0000u); }

// LDS-only barrier: orders ds ops across waves but does NOT drain vmcnt --
// global loads stay in flight and nontemporal stores never block the barrier.
static __device__ __forceinline__ void lds_barrier() {
    asm volatile("s_waitcnt lgkmcnt(0)" ::: "memory");
    __builtin_amdgcn_s_barrier();
}

// 256 blocks (1/CU), 1024 threads, 2 batches/block, 4x32KB LDS quarter-buffers.
// = R18 (47.26us, proven no-spill) + ONE change: batch-B's first two
// quarter-loads issue BEFORE the SUMS/COEF bubble, so the HBM read engine
// stays busy through it. Reuses the dead a/e register sets -- zero extra
// register pressure (R19's in-register coefs spilled: WRITE 131->157 MB).
__global__ __launch_bounds__(1024, 4) void ephaptic_pipe(const float* __restrict__ x,
                                                         const float* __restrict__ w,
                                                         float* __restrict__ out) {
    const int tid = threadIdx.x;
    const int b0 = blockIdx.x * 2;

    __shared__ uint32_t sx[4][M_][256];     // 4 quarter-buffers, bf16 pairs (32 KB each)
    __shared__ float sT[M_], sF[M_], sL[M_];
    __shared__ fvec4 sCA[M_], sCB[M_];

    // R-mapping: thread (m,t) covers row m, 4 float4s per quarter
    const int m = tid >> 5;
    const int t = tid & 31;
    // W-mapping: thread (rg,p4) covers col4 p4 for rows rg*4..rg*4+3
    const int p4 = tid & 127;
    const int rg = tid >> 7;

    const fvec4* wf = (const fvec4*)w;

    float psum = 0.f, first = 0.f, last = 0.f;
    fvec4 a0, a1, a2, a3;   // load set A (even quarters)
    fvec4 e0, e1, e2, e3;   // load set B (odd quarters)

    auto RL = [&](int b, int rq, fvec4& v0, fvec4& v1, fvec4& v2, fvec4& v3) {
        const fvec4* row = (const fvec4*)(x + ((size_t)b * M_ + m) * (size_t)D_) + rq * Q4;
        v0 = row[t];  v1 = row[t + 32];  v2 = row[t + 64];  v3 = row[t + 96];
    };
    auto RS = [&](int rq, const fvec4& v0, const fvec4& v1, const fvec4& v2, const fvec4& v3) {
        psum += (v0.x+v0.y)+(v0.z+v0.w) + (v1.x+v1.y)+(v1.z+v1.w)
              + (v2.x+v2.y)+(v2.z+v2.w) + (v3.x+v3.y)+(v3.z+v3.w);
        if (rq == 0 && t == 0)  first = v0.x;   // x[m][0]
        if (rq == 3 && t == 31) last  = v3.w;   // x[m][2047]
        uint2* sr = (uint2*)sx[rq][m];
        sr[t]      = make_uint2(pk_bf16(v0.x, v0.y), pk_bf16(v0.z, v0.w));
        sr[t + 32] = make_uint2(pk_bf16(v1.x, v1.y), pk_bf16(v1.z, v1.w));
        sr[t + 64] = make_uint2(pk_bf16(v2.x, v2.y), pk_bf16(v2.z, v2.w));
        sr[t + 96] = make_uint2(pk_bf16(v3.x, v3.y), pk_bf16(v3.z, v3.w));
    };
    auto SUMS = [&]() {
        float s = psum;
#pragma unroll
        for (int off = 16; off > 0; off >>= 1) s += __shfl_xor(s, off, 64);
        if (t == 0)  { sT[m] = s; sF[m] = first; }
        if (t == 31) { sL[m] = last; }
    };
    auto COEF = [&](fvec4* sC) {
        if (tid < M_) {
            const int i = tid;
            float r0 = 0.f, r1 = 0.f, r2 = 0.f;
            for (int j = 0; j < M_; ++j) {
                if (j == i) continue;
                const float dij = __expf(-0.5f * fabsf((float)(i - j)));
                const float T = sT[j];
                r0 += dij * (T - sL[j]);
                r1 += dij * T;
                r2 += dij * (T - sF[j]);
            }
            const float s = 0.1f / (float)D_;
            sC[i] = (fvec4){r0 * s, r1 * s, r2 * s, 0.f};
        }
    };
    auto W = [&](int b, int wq, const fvec4* sC) {
        const fvec4 w0 = wf[(wq * Q4 + p4) * 3 + 0];
        const fvec4 w1 = wf[(wq * Q4 + p4) * 3 + 1];
        const fvec4 w2 = wf[(wq * Q4 + p4) * 3 + 2];
        fvec4* ob = (fvec4*)(out + (size_t)b * M_ * D_) + wq * Q4 + p4;
#pragma unroll
        for (int rr = 0; rr < 4; ++rr) {
            const int r = rg * 4 + rr;
            const fvec4 c = sC[r];
            const uint2 u = ((const uint2*)sx[wq][r])[p4];
            fvec4 o;
            o.x = bf_lo(u.x) + c.x * w0.x + c.y * w0.y + c.z * w0.z;
            o.y = bf_hi(u.x) + c.x * w0.w + c.y * w1.x + c.z * w1.y;
            o.z = bf_lo(u.y) + c.x * w1.z + c.y * w1.w + c.z * w2.x;
            o.w = bf_hi(u.y) + c.x * w2.y + c.y * w2.z + c.z * w2.w;
            __builtin_nontemporal_store(o, ob + (size_t)r * 512);
        }
    };

    // ---- batch A reads: 2-deep register pipeline
    RL(b0, 0, a0, a1, a2, a3);
    RL(b0, 1, e0, e1, e2, e3);
    RS(0, a0, a1, a2, a3);  RL(b0, 2, a0, a1, a2, a3);
    RS(1, e0, e1, e2, e3);  RL(b0, 3, e0, e1, e2, e3);
    RS(2, a0, a1, a2, a3);
    RS(3, e0, e1, e2, e3);
    SUMS();
    // early-issue batch B quarters 0,1: in flight through the coef bubble
    RL(b0 + 1, 0, a0, a1, a2, a3);
    RL(b0 + 1, 1, e0, e1, e2, e3);
    lds_barrier();
    COEF(sCA);
    lds_barrier();

    // ---- middle: write A quarter-by-quarter; batch B loads prefetched
    W(b0, 0, sCA);
    lds_barrier();
    psum = 0.f;
    RS(0, a0, a1, a2, a3);  RL(b0 + 1, 2, a0, a1, a2, a3);  W(b0, 1, sCA);
    lds_barrier();
    RS(1, e0, e1, e2, e3);  RL(b0 + 1, 3, e0, e1, e2, e3);  W(b0, 2, sCA);
    lds_barrier();
    RS(2, a0, a1, a2, a3);  W(b0, 3, sCA);
    lds_barrier();
    RS(3, e0, e1, e2, e3);
    SUMS();
    lds_barrier();
    COEF(sCB);
    lds_barrier();

    // ---- batch B: drain writes (stores retire past endpgm)
    W(b0 + 1, 0, sCB);
    W(b0 + 1, 1, sCB);
    W(b0 + 1, 2, sCB);
    W(b0 + 1, 3, sCB);
}

extern "C" void kernel_launch(void* const* d_in, const int* in_sizes, int n_in,
                              void* d_out, int out_size, void* d_ws, size_t ws_size,
                              hipStream_t stream) {
    const float* x = (const float*)d_in[0];
    const float* w = (const float*)d_in[1];
    float* out = (float*)d_out;
    ephaptic_pipe<<<B_ / 2, 1024, 0, stream>>>(x, w, out);
}